// Round 13
// baseline (624.292 us; speedup 1.0000x reference)
//
#include <hip/hip_runtime.h>
#include <hip/hip_bf16.h>
#include <stdint.h>

typedef unsigned short u16;
typedef unsigned int u32;
typedef unsigned long long u64;
typedef short v8s __attribute__((ext_vector_type(8)));
typedef float v4f __attribute__((ext_vector_type(4)));

__device__ __forceinline__ float bf2f(u16 u) {
  union { u32 i; float f; } c; c.i = ((u32)u) << 16; return c.f;
}
__device__ __forceinline__ u16 f2bf(float f) {
  u32 x = __float_as_uint(f);
  u32 r = (x + 0x7fffu + ((x >> 16) & 1u)) >> 16;
  return (u16)r;
}

#define LOG2E 1.44269504088896340736f

// ---------------- mask packing: adj [4096][4096] int -> bitmask [4096][64] u64
__global__ __launch_bounds__(256) void k_pack_mask(const int* __restrict__ adj,
                                                   u64* __restrict__ maskb) {
  int gid = blockIdx.x * 256 + threadIdx.x;
  int word = gid >> 6;
  int lane = threadIdx.x & 63;
  int v = adj[(size_t)word * 64 + lane];
  u64 b = __ballot(v > 0);
  if (lane == 0) maskb[word] = b;
}

// ---------------- fused lin1+lin2: x[4096][128] (f32) -> h2[4096][64] (bf16)
__global__ __launch_bounds__(64) void k_lin12(const float* __restrict__ x,
    const float* __restrict__ w1, const float* __restrict__ b1,
    const float* __restrict__ w2, const float* __restrict__ b2,
    u16* __restrict__ h2) {
  __shared__ float xr[128];
  __shared__ float h1r[64];
  int i = blockIdx.x, t = threadIdx.x;
  xr[t] = x[i * 128 + t];
  xr[t + 64] = x[i * 128 + 64 + t];
  __syncthreads();
  float a1 = b1[t];
  for (int k = 0; k < 128; ++k) a1 += xr[k] * w1[k * 64 + t];
  h1r[t] = a1;
  __syncthreads();
  float a2 = b2[t];
  for (int k = 0; k < 64; ++k) a2 += h1r[k] * w2[k * 64 + t];
  h2[i * 64 + t] = f2bf(a2);
}

// ---------------- batched transpose+cast: W [Bh][K][F] f32 -> WT [Bh*F][K] bf16
__global__ __launch_bounds__(256) void k_transpose(const float* __restrict__ W,
                                                   u16* __restrict__ WT,
                                                   int K, int F, int total) {
  int idx = blockIdx.x * 256 + threadIdx.x;
  if (idx >= total) return;
  int kf = K * F;
  int h = idx / kf;
  int r = idx - h * kf;
  int k = r / F;
  int f = r - k * F;
  WT[((size_t)h * F + f) * K + k] = f2bf(W[idx]);
}

// ---------------- bf16 GEMM  D[m][n] = sum_k A[m][k]*B[n][k]  (both k-contiguous)
// LDS stride 72 u16: row-dependent bank rotation kills the 16-way conflict.
// D is written in MFMA-FRAGMENT layout for k_agg (u16 offset):
//   (m>>8)<<20 | jb*16384 + kk2*8192 + wv*2048 + ft*512 + (lq*16+lr)*8 + b
__global__ __launch_bounds__(256) void k_gemm_bt(const u16* __restrict__ A,
    const u16* __restrict__ B, u16* __restrict__ D, int M, int Nn, int K) {
  __shared__ u16 As[128 * 72];
  __shared__ u16 Bs[128 * 72];
  const int tid = threadIdx.x, wv = tid >> 6, lane = tid & 63;
  const int tile_n = blockIdx.x * 128, tile_m = blockIdx.y * 128;
  const int lr = lane & 15, lq = lane >> 4;
  const int wr = wv >> 1, wc = wv & 1;
  const int srow = lane >> 3, scol = (lane & 7) * 8;
  v4f acc[4][4] = {};
  for (int kb = 0; kb < K; kb += 64) {
    uint4 ra[4], rb4[4];
#pragma unroll
    for (int r = 0; r < 4; ++r) {
      int rowi = wv * 32 + r * 8 + srow;
      ra[r] = *(const uint4*)(A + (size_t)(tile_m + rowi) * K + kb + scol);
      rb4[r] = *(const uint4*)(B + (size_t)(tile_n + rowi) * K + kb + scol);
    }
#pragma unroll
    for (int r = 0; r < 4; ++r) {
      int rowi = wv * 32 + r * 8 + srow;
      *(uint4*)&As[rowi * 72 + scol] = ra[r];
      *(uint4*)&Bs[rowi * 72 + scol] = rb4[r];
    }
    __syncthreads();
#pragma unroll
    for (int kk = 0; kk < 64; kk += 32) {
      v8s af[4], bfr[4];
#pragma unroll
      for (int it = 0; it < 4; ++it)
        af[it] = *(const v8s*)&As[(wr * 64 + it * 16 + lr) * 72 + kk + lq * 8];
#pragma unroll
      for (int ft = 0; ft < 4; ++ft)
        bfr[ft] = *(const v8s*)&Bs[(wc * 64 + ft * 16 + lr) * 72 + kk + lq * 8];
#pragma unroll
      for (int it = 0; it < 4; ++it)
#pragma unroll
        for (int ft = 0; ft < 4; ++ft)
          acc[it][ft] = __builtin_amdgcn_mfma_f32_16x16x32_bf16(af[it], bfr[ft], acc[it][ft], 0, 0, 0);
    }
    __syncthreads();
  }
#pragma unroll
  for (int it = 0; it < 4; ++it)
#pragma unroll
    for (int ft = 0; ft < 4; ++ft)
#pragma unroll
      for (int r = 0; r < 4; ++r) {
        int m = tile_m + wr * 64 + it * 16 + lq * 4 + r;
        int n = tile_n + wc * 64 + ft * 16 + lr;
        size_t addr = ((size_t)(m >> 8) << 20)
                    + (size_t)((n >> 6) * 16384 + ((n >> 5) & 1) * 8192
                    + (((m & 255) >> 6)) * 2048 + ((m >> 4) & 3) * 512
                    + (((n >> 3) & 3) * 16 + (m & 15)) * 8 + (n & 7));
        D[addr] = f2bf(acc[it][ft][r]);
      }
}

// ---------------- wa[h][2][Fin] = W[h] @ a[h] halves (all f32)
__global__ __launch_bounds__(256) void k_wa(const float* __restrict__ W,
    const float* __restrict__ a, float* __restrict__ wa, int Fin, int F, int total) {
  int idx = blockIdx.x * blockDim.x + threadIdx.x;
  if (idx >= total) return;
  int h = idx / (2 * Fin);
  int r = idx - h * 2 * Fin;
  int which = r / Fin;
  int k = r - which * Fin;
  const float* Wh = W + (size_t)h * Fin * F + (size_t)k * F;
  const float* ah = a + (size_t)h * 2 * F + which * F;
  float sacc = 0.0f;
  for (int f = 0; f < F; ++f) sacc += Wh[f] * ah[f];
  wa[idx] = sacc;
}

// ---------------- s[h][j], t[h][j] = Hin[j] . wa_src/dst  (Hin bf16)
// Scaled by log2(e): downstream exp() becomes bare v_exp_f32 (exp2).
__global__ __launch_bounds__(256) void k_st2(const u16* __restrict__ Hin,
    const float* __restrict__ wa, int Fin, float* __restrict__ s, float* __restrict__ t) {
  int h = blockIdx.y;
  int row = blockIdx.x * 4 + (threadIdx.x >> 6);
  int lane = threadIdx.x & 63;
  const float* wsrc = wa + (size_t)h * 2 * Fin;
  const float* wdst = wsrc + Fin;
  const u16* hr = Hin + (size_t)row * Fin;
  float ps = 0.0f, pt = 0.0f;
  for (int k = lane; k < Fin; k += 64) {
    float v = bf2f(hr[k]);
    ps += v * wsrc[k];
    pt += v * wdst[k];
  }
#pragma unroll
  for (int o = 32; o; o >>= 1) { ps += __shfl_xor(ps, o); pt += __shfl_xor(pt, o); }
  if (lane == 0) { s[h * 4096 + row] = ps * LOG2E; t[h * 4096 + row] = pt * LOG2E; }
}

// ---------------- per-row masked max -> m_i only (sum computed in k_agg)
__global__ __launch_bounds__(256) void k_rowstats(const u64* __restrict__ maskb,
    const float* __restrict__ s, const float* __restrict__ t,
    float* __restrict__ m) {
  __shared__ float red[4];
  const int h = blockIdx.y;
  const int row = blockIdx.x;
  const int tid = threadIdx.x;
  const int wv = tid >> 6, lane = tid & 63;
  const float* tb = t + h * 4096;
  const u64* mrow = maskb + (size_t)row * 64;
  float tmax = -INFINITY;
#pragma unroll
  for (int i = 0; i < 4; ++i) {
    int jb = i * 1024 + tid * 4;
    u64 w = mrow[jb >> 6];
    int sh = jb & 63;
    float4 tv = *(const float4*)(tb + jb);
    if ((w >> sh) & 1ull) tmax = fmaxf(tmax, tv.x);
    if ((w >> (sh + 1)) & 1ull) tmax = fmaxf(tmax, tv.y);
    if ((w >> (sh + 2)) & 1ull) tmax = fmaxf(tmax, tv.z);
    if ((w >> (sh + 3)) & 1ull) tmax = fmaxf(tmax, tv.w);
  }
#pragma unroll
  for (int o = 32; o; o >>= 1) tmax = fmaxf(tmax, __shfl_xor(tmax, o));
  if (lane == 0) red[wv] = tmax;
  __syncthreads();
  if (tid == 0) {
    tmax = fmaxf(fmaxf(red[0], red[1]), fmaxf(red[2], red[3]));
    float si = s[h * 4096 + row];
    float e0 = si + tmax;
    float mi = fmaxf(e0, 0.2f * e0);
    if (tmax == -INFINITY) mi = 0.0f;
    m[h * 4096 + row] = mi;
  }
}

// ---- P-tile load/compute split (round 13): tv/mask loads are issued BEFORE the
// rb fragment loads so that waiting on tv (vmcnt FIFO drains oldest-first, m135)
// does NOT drain the 16 rb loads. p_comp is pure VALU.
struct PL { float tv[8]; u32 w32; };

__device__ __forceinline__ PL p_load(const float* __restrict__ tb,
    const u64* __restrict__ mrow, int jb, int jc) {
  PL r;
  r.w32 = (u32)(mrow[jb] >> jc);
  const float4* tp = (const float4*)(tb + jb * 64 + jc);
  *(float4*)&r.tv[0] = tp[0];
  *(float4*)&r.tv[4] = tp[1];
  return r;
}

__device__ __forceinline__ float p_comp(const PL& pl, float c1, float c2,
                                        u16* __restrict__ dst) {
  u32 pk[4];
  float ps = 0.0f;
#pragma unroll
  for (int q = 0; q < 4; ++q) {
    float t0 = pl.tv[2 * q], t1 = pl.tv[2 * q + 1];
    float p0 = exp2f(fmaxf(t0 + c1, fmaf(0.2f, t0, c2)));
    p0 = (pl.w32 & (1u << (2 * q))) ? p0 : 0.0f;
    float p1 = exp2f(fmaxf(t1 + c1, fmaf(0.2f, t1, c2)));
    p1 = (pl.w32 & (1u << (2 * q + 1))) ? p1 : 0.0f;
    ps += p0 + p1;
    union { __hip_bfloat162 h; u32 u; } cv;
    cv.h = __float22bfloat162_rn(make_float2(p0, p1));
    pk[q] = cv.u;
  }
  *(uint4*)dst = *(uint4*)&pk[0];
  return ps;
}

// ---------------- masked-softmax aggregation, 32-row tiles, 2 jb per barrier
// hpT in FRAGMENT layout; 16 coalesced 1 KB B-fragment loads per interval.
// Interval: p_load(jb+2,jb+3) FIRST -> issue rb(jb,jb+1) -> p_comp (VALU covers
// rb latency; tv already in flight ahead of rb in the vmcnt FIFO) ->
// setprio(1) MFMA setprio(0) -> ONE barrier. No value crosses a barrier.
__global__ __launch_bounds__(256) void k_agg(const u16* __restrict__ hpT,
    const u64* __restrict__ maskb, const float* __restrict__ s, const float* __restrict__ t,
    const float* __restrict__ m, float* __restrict__ sumF,
    u16* __restrict__ outB, float* __restrict__ outF,
    int out_ld, int stats_stride, int do_relu, int use_atomic) {
  __shared__ u16 Pt[2][2][32 * 72];
  __shared__ float linv_sh[32];

  const int tid = threadIdx.x;
  const int wv = tid >> 6;
  const int lane = tid & 63;
  const int i0 = blockIdx.x * 32;
  const int gy = blockIdx.y;

  const u16* hbF = hpT + ((size_t)gy << 20);
  const float* sb = s + gy * stats_stride;
  const float* tb = t + gy * stats_stride;
  const float* mb = m + gy * stats_stride;

  const int il = tid >> 3;           // local row 0..31
  const int jc = (tid & 7) * 8;      // 8-wide j chunk
  const float si = sb[i0 + il];
  const float mi = mb[i0 + il];
  const float c1 = si - mi;
  const float c2 = 0.2f * si - mi;
  const u64* mrow = maskb + (size_t)(i0 + il) * 64;

  const int lr = lane & 15;
  const int lq = lane >> 4;

  v4f acc[2][4] = {};
  float psum = 0.0f;

  const int njb = 64 / gridDim.z;
  const int jb0 = blockIdx.z * njb;
  const int jbend = jb0 + njb;

  // per-wave fragment base: [jb][kk2][wv][ft][lane] (u16 units)
  const u16* fb = hbF + wv * 2048 + lane * 8;

  // ---- prologue: P(jb0), P(jb0+1)
  {
    PL a0 = p_load(tb, mrow, jb0, jc);
    PL a1 = p_load(tb, mrow, jb0 + 1, jc);
    psum += p_comp(a0, c1, c2, &Pt[0][0][il * 72 + jc]);
    psum += p_comp(a1, c1, c2, &Pt[0][1][il * 72 + jc]);
  }
  __syncthreads();

  int cur = 0;
  for (int jb = jb0; jb < jbend; jb += 2) {
    const bool havep = (jb + 2 < jbend);
    // 1. issue tv/mask loads for next interval's P FIRST (ahead of rb in FIFO)
    PL pl0, pl1;
    if (havep) {
      pl0 = p_load(tb, mrow, jb + 2, jc);
      pl1 = p_load(tb, mrow, jb + 3, jc);
    }

    // 2. issue 16 B-fragment loads for jb, jb+1
    v8s rb[2][2][4];
#pragma unroll
    for (int sub = 0; sub < 2; ++sub) {
      const u16* fj = fb + (size_t)(jb + sub) * 16384;
#pragma unroll
      for (int kk2 = 0; kk2 < 2; ++kk2)
#pragma unroll
        for (int ft = 0; ft < 4; ++ft)
          rb[sub][kk2][ft] = *(const v8s*)(fj + kk2 * 8192 + ft * 512);
    }

    // 3. P(jb+2), P(jb+3) -> Pt[cur^1]  (VALU covers the rb loads)
    if (havep) {
      psum += p_comp(pl0, c1, c2, &Pt[cur ^ 1][0][il * 72 + jc]);
      psum += p_comp(pl1, c1, c2, &Pt[cur ^ 1][1][il * 72 + jc]);
    }

    // 4. MFMA for both sub-tiles (prioritized: keep matrix pipe fed)
    __builtin_amdgcn_s_setprio(1);
#pragma unroll
    for (int sub = 0; sub < 2; ++sub) {
#pragma unroll
      for (int kk2 = 0; kk2 < 2; ++kk2) {
        v8s af[2];
#pragma unroll
        for (int it = 0; it < 2; ++it)
          af[it] = *(const v8s*)&Pt[cur][sub][(it * 16 + lr) * 72 + kk2 * 32 + lq * 8];
#pragma unroll
        for (int it = 0; it < 2; ++it)
#pragma unroll
          for (int ft = 0; ft < 4; ++ft)
            acc[it][ft] = __builtin_amdgcn_mfma_f32_16x16x32_bf16(af[it], rb[sub][kk2][ft], acc[it][ft], 0, 0, 0);
      }
    }
    __builtin_amdgcn_s_setprio(0);
    __syncthreads();
    cur ^= 1;
  }

  // row-sum reduce over the 8 threads of each P-row (consecutive lanes)
  psum += __shfl_xor(psum, 1);
  psum += __shfl_xor(psum, 2);
  psum += __shfl_xor(psum, 4);
  if ((tid & 7) == 0) {
    if (use_atomic) {
      if (gy == 0) atomicAdd(&sumF[i0 + il], psum);
    } else {
      linv_sh[il] = psum > 0.0f ? 1.0f / psum : 0.0f;
    }
  }
  __syncthreads();

#pragma unroll
  for (int it = 0; it < 2; ++it)
#pragma unroll
    for (int ft = 0; ft < 4; ++ft)
#pragma unroll
      for (int r = 0; r < 4; ++r) {
        int ilocal = it * 16 + lq * 4 + r;
        int col = gy * 256 + wv * 64 + ft * 16 + lr;
        if (use_atomic) {
          atomicAdd(&outF[(size_t)(i0 + ilocal) * out_ld + col], acc[it][ft][r]);
        } else {
          float v = acc[it][ft][r] * linv_sh[ilocal];
          if (do_relu) v = fmaxf(v, 0.0f);
          outB[(size_t)(i0 + ilocal) * out_ld + col] = f2bf(v);
        }
      }
}

// ---------------- finalize j-split partials (divide by accumulated row sums)
__global__ __launch_bounds__(256) void k_fin_bf(const float* __restrict__ outF,
    const float* __restrict__ sums, u16* __restrict__ outB, int F, int do_relu) {
  size_t idx = (size_t)blockIdx.x * 256 + threadIdx.x;
  int row = (int)(idx / F);
  float sm = sums[row];
  float linv = sm > 0.0f ? 1.0f / sm : 0.0f;
  float v = outF[idx] * linv;
  if (do_relu) v = fmaxf(v, 0.0f);
  outB[idx] = f2bf(v);
}
__global__ __launch_bounds__(256) void k_fin_f32(float* __restrict__ outF,
    const float* __restrict__ sums, int F) {
  size_t idx = (size_t)blockIdx.x * 256 + threadIdx.x;
  int row = (int)(idx / F);
  float sm = sums[row];
  float linv = sm > 0.0f ? 1.0f / sm : 0.0f;
  outF[idx] *= linv;
}

// ---------------- GroupNorm(1 group over everything) reduce + apply (in place)
// Atomic-contention fix (round 12): 256 WGs, wave-reduce -> LDS cross-wave
// reduce -> ONE thread per WG atomicAdds = 512 atomics total.
__global__ __launch_bounds__(256) void k_gn_reduce(const u16* __restrict__ h4,
                                                   float* __restrict__ accv) {
  __shared__ float redS[8];
  const size_t total = (size_t)4096 * 1536 / 8;
  const int tid = threadIdx.x;
  const int wv = tid >> 6;
  float sm = 0.0f, s2 = 0.0f;
  for (size_t c = (size_t)blockIdx.x * 256 + tid; c < total; c += (size_t)gridDim.x * 256) {
    uint4 u = ((const uint4*)h4)[c];
    u16 us[8];
    *(uint4*)us = u;
#pragma unroll
    for (int k = 0; k < 8; ++k) {
      float v = bf2f(us[k]);
      sm += v;
      s2 += v * v;
    }
  }
#pragma unroll
  for (int o = 32; o; o >>= 1) { sm += __shfl_xor(sm, o); s2 += __shfl_xor(s2, o); }
  if ((tid & 63) == 0) { redS[wv * 2] = sm; redS[wv * 2 + 1] = s2; }
  __syncthreads();
  if (tid == 0) {
    float tsm = redS[0] + redS[2] + redS[4] + redS[6];
    float ts2 = redS[1] + redS[3] + redS[5] + redS[7];
    atomicAdd(&accv[0], tsm);
    atomicAdd(&accv[1], ts2);
  }
}

__global__ __launch_bounds__(256) void k_gn_apply(const u16* __restrict__ h4,
    const float* __restrict__ accv, const float* __restrict__ gw,
    const float* __restrict__ gb, u16* __restrict__ h5) {
  const float Mc = 4096.0f * 1536.0f;
  float mu = accv[0] * (1.0f / Mc);
  float var = (accv[1] - Mc * mu * mu) * (1.0f / (Mc - 1.0f));
  float rstd = rsqrtf(var + 1e-5f);
  size_t c = (size_t)blockIdx.x * 256 + threadIdx.x;
  uint4 u = ((const uint4*)h4)[c];
  u16 us[8], os[8];
  *(uint4*)us = u;
  int col0 = (int)((c * 8) % 1536);
#pragma unroll
  for (int k = 0; k < 8; ++k) {
    float v = (bf2f(us[k]) - mu) * rstd * gw[col0 + k] + gb[col0 + k];
    os[k] = f2bf(v);
  }
  ((uint4*)h5)[c] = *(uint4*)os;
}

extern "C" void kernel_launch(void* const* d_in, const int* in_sizes, int n_in,
                              void* d_out, int out_size, void* d_ws, size_t ws_size,
                              hipStream_t stream) {
  const float* x = (const float*)d_in[0];
  const int* adj = (const int*)d_in[1];
  const float* lin1_w = (const float*)d_in[2];
  const float* lin1_b = (const float*)d_in[3];
  const float* lin2_w = (const float*)d_in[4];
  const float* lin2_b = (const float*)d_in[5];
  const float* conv1_W = (const float*)d_in[6];
  const float* conv1_a = (const float*)d_in[7];
  const float* att_W = (const float*)d_in[8];
  const float* att_a = (const float*)d_in[9];
  const float* gn_w = (const float*)d_in[10];
  const float* gn_b = (const float*)d_in[11];
  const float* conv2_W = (const float*)d_in[12];
  const float* conv2_a = (const float*)d_in[13];
  float* out = (float*)d_out;   // reference output dtype: float32

  // ---- arena, adaptive: big path needs 32.5 MB (6-head batch), small path 23.75 MB
  const bool big = ws_size >= (34ull << 20);
  const int B = big ? 6 : 2;           // heads per batch
  char* base = (char*)d_ws;
  const size_t MB = 1ull << 20;
  u64* maskb = (u64*)base;                                   // 2 MB
  u16* hpT = (u16*)(base + 2 * MB);                          // big 12 / small 4 MB
  u16* hC  = (u16*)(base + (big ? 14 : 6) * MB);             // 12 MB (h4/h5)
  u16* h3  = (u16*)(base + (big ? 26 : 18) * MB);            // 4 MB
  u16* h2  = (u16*)(base + (big ? 30 : 22) * MB);            // 0.5 MB
  u16* wt  = (u16*)(base + (big ? 30 : 22) * MB + 512 * 1024);      // 1.5 MB
  float* sA = (float*)(base + (big ? 32 : 24) * MB);         // stats 0.5 MB
  float* tA = sA + 6 * 4096;
  float* mA = tA + 6 * 4096;
  float* lA = mA + 6 * 4096;      // row-sum accumulator for j-split launches
  float* wab = lA + 6 * 4096;
  float* gacc = wab + 8192;
  float* outF1 = (float*)hC;   // conv1 fp32 partials (8 MB) — h4 not yet live

  hipMemsetAsync(gacc, 0, 16, stream);
  hipMemsetAsync(out, 0, (size_t)4096 * 256 * 4, stream);
  hipMemsetAsync(outF1, 0, (size_t)4096 * 512 * 4, stream);
  hipMemsetAsync(lA, 0, 4096 * 4, stream);

  k_pack_mask<<<dim3(65536), dim3(256), 0, stream>>>(adj, maskb);
  k_lin12<<<dim3(4096), dim3(64), 0, stream>>>(x, lin1_w, lin1_b, lin2_w, lin2_b, h2);

  // ---- conv1 (F=512): j-split Z=4 (1024 WGs = 4 WG/CU)
  k_transpose<<<dim3(128), dim3(256), 0, stream>>>(conv1_W, wt, 64, 512, 64 * 512);
  k_gemm_bt<<<dim3(32, 4), dim3(256), 0, stream>>>(wt, h2, hpT, 512, 4096, 64);
  k_wa<<<dim3(1), dim3(128), 0, stream>>>(conv1_W, conv1_a, wab, 64, 512, 128);
  k_st2<<<dim3(1024, 1), dim3(256), 0, stream>>>(h2, wab, 64, sA, tA);
  k_rowstats<<<dim3(4096, 1), dim3(256), 0, stream>>>(maskb, sA, tA, mA);
  k_agg<<<dim3(128, 2, 4), dim3(256), 0, stream>>>(hpT, maskb, sA, tA, mA, lA,
                                                   (u16*)0, outF1, 512, 0, 0, 1);
  k_fin_bf<<<dim3(8192), dim3(256), 0, stream>>>(outF1, lA, h3, 512, 1);

  // ---- 6 heads (F=256), batched B at a time; stats batched once
  k_wa<<<dim3(24), dim3(256), 0, stream>>>(att_W, att_a, wab, 512, 256, 6144);
  k_st2<<<dim3(1024, 6), dim3(256), 0, stream>>>(h3, wab, 512, sA, tA);
  k_rowstats<<<dim3(4096, 6), dim3(256), 0, stream>>>(maskb, sA, tA, mA);
  for (int bh = 0; bh < 6; bh += B) {
    k_transpose<<<dim3(B * 512), dim3(256), 0, stream>>>(att_W + (size_t)bh * 512 * 256,
                                                         wt, 512, 256, B * 512 * 256);
    k_gemm_bt<<<dim3(32, 2 * B), dim3(256), 0, stream>>>(wt, h3, hpT, B * 256, 4096, 512);
    k_agg<<<dim3(128, B, 1), dim3(256), 0, stream>>>(hpT, maskb,
        sA + bh * 4096, tA + bh * 4096, mA + bh * 4096, (float*)0,
        hC + bh * 256, (float*)0, 1536, 4096, 1, 0);
  }

  // ---- GroupNorm (in place on hC)
  k_gn_reduce<<<dim3(256), dim3(256), 0, stream>>>(hC, gacc);
  k_gn_apply<<<dim3(3072), dim3(256), 0, stream>>>(hC, gacc, gn_w, gn_b, hC);

  // ---- conv2 (F=256): j-split Z=8 (1024 WGs = 4 WG/CU), atomics into f32 d_out
  k_transpose<<<dim3(1536), dim3(256), 0, stream>>>(conv2_W, wt, 1536, 256, 1536 * 256);
  k_gemm_bt<<<dim3(32, 2), dim3(256), 0, stream>>>(wt, hC, hpT, 256, 4096, 1536);
  k_wa<<<dim3(12), dim3(256), 0, stream>>>(conv2_W, conv2_a, wab, 1536, 256, 3072);
  k_st2<<<dim3(1024, 1), dim3(256), 0, stream>>>(hC, wab, 1536, sA, tA);
  k_rowstats<<<dim3(4096, 1), dim3(256), 0, stream>>>(maskb, sA, tA, mA);
  hipMemsetAsync(lA, 0, 4096 * 4, stream);
  k_agg<<<dim3(128, 1, 8), dim3(256), 0, stream>>>(hpT, maskb, sA, tA, mA, lA,
                                                   (u16*)0, out, 256, 0, 0, 1);
  k_fin_f32<<<dim3(4096), dim3(256), 0, stream>>>(out, lA, 256);
}

// Round 14
// 601.220 us; speedup vs baseline: 1.0384x; 1.0384x over previous
//
#include <hip/hip_runtime.h>
#include <hip/hip_bf16.h>
#include <stdint.h>

typedef unsigned short u16;
typedef unsigned int u32;
typedef unsigned long long u64;
typedef short v8s __attribute__((ext_vector_type(8)));
typedef float v4f __attribute__((ext_vector_type(4)));

__device__ __forceinline__ float bf2f(u16 u) {
  union { u32 i; float f; } c; c.i = ((u32)u) << 16; return c.f;
}
__device__ __forceinline__ u16 f2bf(float f) {
  u32 x = __float_as_uint(f);
  u32 r = (x + 0x7fffu + ((x >> 16) & 1u)) >> 16;
  return (u16)r;
}

#define LOG2E 1.44269504088896340736f

// ---------------- mask packing: adj [4096][4096] int -> bitmask [4096][64] u64
__global__ __launch_bounds__(256) void k_pack_mask(const int* __restrict__ adj,
                                                   u64* __restrict__ maskb) {
  int gid = blockIdx.x * 256 + threadIdx.x;
  int word = gid >> 6;
  int lane = threadIdx.x & 63;
  int v = adj[(size_t)word * 64 + lane];
  u64 b = __ballot(v > 0);
  if (lane == 0) maskb[word] = b;
}

// ---------------- fused lin1+lin2: x[4096][128] (f32) -> h2[4096][64] (bf16)
__global__ __launch_bounds__(64) void k_lin12(const float* __restrict__ x,
    const float* __restrict__ w1, const float* __restrict__ b1,
    const float* __restrict__ w2, const float* __restrict__ b2,
    u16* __restrict__ h2) {
  __shared__ float xr[128];
  __shared__ float h1r[64];
  int i = blockIdx.x, t = threadIdx.x;
  xr[t] = x[i * 128 + t];
  xr[t + 64] = x[i * 128 + 64 + t];
  __syncthreads();
  float a1 = b1[t];
  for (int k = 0; k < 128; ++k) a1 += xr[k] * w1[k * 64 + t];
  h1r[t] = a1;
  __syncthreads();
  float a2 = b2[t];
  for (int k = 0; k < 64; ++k) a2 += h1r[k] * w2[k * 64 + t];
  h2[i * 64 + t] = f2bf(a2);
}

// ---------------- batched transpose+cast: W [Bh][K][F] f32 -> WT [Bh*F][K] bf16
__global__ __launch_bounds__(256) void k_transpose(const float* __restrict__ W,
                                                   u16* __restrict__ WT,
                                                   int K, int F, int total) {
  int idx = blockIdx.x * 256 + threadIdx.x;
  if (idx >= total) return;
  int kf = K * F;
  int h = idx / kf;
  int r = idx - h * kf;
  int k = r / F;
  int f = r - k * F;
  WT[((size_t)h * F + f) * K + k] = f2bf(W[idx]);
}

// ---------------- bf16 GEMM  D[m][n] = sum_k A[m][k]*B[n][k]  (both k-contiguous)
// LDS stride 72 u16: row-dependent bank rotation kills the 16-way conflict.
// D is written in MFMA-FRAGMENT layout for k_agg (u16 offset):
//   (m>>8)<<20 | jb*16384 + kk2*8192 + wv*2048 + ft*512 + (lq*16+lr)*8 + b
__global__ __launch_bounds__(256) void k_gemm_bt(const u16* __restrict__ A,
    const u16* __restrict__ B, u16* __restrict__ D, int M, int Nn, int K) {
  __shared__ u16 As[128 * 72];
  __shared__ u16 Bs[128 * 72];
  const int tid = threadIdx.x, wv = tid >> 6, lane = tid & 63;
  const int tile_n = blockIdx.x * 128, tile_m = blockIdx.y * 128;
  const int lr = lane & 15, lq = lane >> 4;
  const int wr = wv >> 1, wc = wv & 1;
  const int srow = lane >> 3, scol = (lane & 7) * 8;
  v4f acc[4][4] = {};
  for (int kb = 0; kb < K; kb += 64) {
    uint4 ra[4], rb4[4];
#pragma unroll
    for (int r = 0; r < 4; ++r) {
      int rowi = wv * 32 + r * 8 + srow;
      ra[r] = *(const uint4*)(A + (size_t)(tile_m + rowi) * K + kb + scol);
      rb4[r] = *(const uint4*)(B + (size_t)(tile_n + rowi) * K + kb + scol);
    }
#pragma unroll
    for (int r = 0; r < 4; ++r) {
      int rowi = wv * 32 + r * 8 + srow;
      *(uint4*)&As[rowi * 72 + scol] = ra[r];
      *(uint4*)&Bs[rowi * 72 + scol] = rb4[r];
    }
    __syncthreads();
#pragma unroll
    for (int kk = 0; kk < 64; kk += 32) {
      v8s af[4], bfr[4];
#pragma unroll
      for (int it = 0; it < 4; ++it)
        af[it] = *(const v8s*)&As[(wr * 64 + it * 16 + lr) * 72 + kk + lq * 8];
#pragma unroll
      for (int ft = 0; ft < 4; ++ft)
        bfr[ft] = *(const v8s*)&Bs[(wc * 64 + ft * 16 + lr) * 72 + kk + lq * 8];
#pragma unroll
      for (int it = 0; it < 4; ++it)
#pragma unroll
        for (int ft = 0; ft < 4; ++ft)
          acc[it][ft] = __builtin_amdgcn_mfma_f32_16x16x32_bf16(af[it], bfr[ft], acc[it][ft], 0, 0, 0);
    }
    __syncthreads();
  }
#pragma unroll
  for (int it = 0; it < 4; ++it)
#pragma unroll
    for (int ft = 0; ft < 4; ++ft)
#pragma unroll
      for (int r = 0; r < 4; ++r) {
        int m = tile_m + wr * 64 + it * 16 + lq * 4 + r;
        int n = tile_n + wc * 64 + ft * 16 + lr;
        size_t addr = ((size_t)(m >> 8) << 20)
                    + (size_t)((n >> 6) * 16384 + ((n >> 5) & 1) * 8192
                    + (((m & 255) >> 6)) * 2048 + ((m >> 4) & 3) * 512
                    + (((n >> 3) & 3) * 16 + (m & 15)) * 8 + (n & 7));
        D[addr] = f2bf(acc[it][ft][r]);
      }
}

// ---------------- wa[h][2][Fin] = W[h] @ a[h] halves (all f32)
__global__ __launch_bounds__(256) void k_wa(const float* __restrict__ W,
    const float* __restrict__ a, float* __restrict__ wa, int Fin, int F, int total) {
  int idx = blockIdx.x * blockDim.x + threadIdx.x;
  if (idx >= total) return;
  int h = idx / (2 * Fin);
  int r = idx - h * 2 * Fin;
  int which = r / Fin;
  int k = r - which * Fin;
  const float* Wh = W + (size_t)h * Fin * F + (size_t)k * F;
  const float* ah = a + (size_t)h * 2 * F + which * F;
  float sacc = 0.0f;
  for (int f = 0; f < F; ++f) sacc += Wh[f] * ah[f];
  wa[idx] = sacc;
}

// ---------------- s[h][j], t[h][j] = Hin[j] . wa_src/dst  (Hin bf16)
// Scaled by log2(e): downstream exp() becomes bare v_exp_f32 (exp2).
// Round 14: vectorized (G13) — v8s bf16 + float4 wa loads, 8 elems/lane/iter.
__global__ __launch_bounds__(256) void k_st2(const u16* __restrict__ Hin,
    const float* __restrict__ wa, int Fin, float* __restrict__ s, float* __restrict__ t) {
  int h = blockIdx.y;
  int row = blockIdx.x * 4 + (threadIdx.x >> 6);
  int lane = threadIdx.x & 63;
  const float* wsrc = wa + (size_t)h * 2 * Fin;
  const float* wdst = wsrc + Fin;
  const u16* hr = Hin + (size_t)row * Fin;
  float ps = 0.0f, pt = 0.0f;
  for (int k0 = lane * 8; k0 < Fin; k0 += 512) {
    v8s hv = *(const v8s*)(hr + k0);
    float4 s0 = *(const float4*)(wsrc + k0);
    float4 s1 = *(const float4*)(wsrc + k0 + 4);
    float4 d0 = *(const float4*)(wdst + k0);
    float4 d1 = *(const float4*)(wdst + k0 + 4);
    float ws[8] = {s0.x, s0.y, s0.z, s0.w, s1.x, s1.y, s1.z, s1.w};
    float wd[8] = {d0.x, d0.y, d0.z, d0.w, d1.x, d1.y, d1.z, d1.w};
#pragma unroll
    for (int q = 0; q < 8; ++q) {
      float v = bf2f((u16)hv[q]);
      ps += v * ws[q];
      pt += v * wd[q];
    }
  }
#pragma unroll
  for (int o = 32; o; o >>= 1) { ps += __shfl_xor(ps, o); pt += __shfl_xor(pt, o); }
  if (lane == 0) { s[h * 4096 + row] = ps * LOG2E; t[h * 4096 + row] = pt * LOG2E; }
}

// ---------------- per-row masked max -> m_i only (sum computed in k_agg)
__global__ __launch_bounds__(256) void k_rowstats(const u64* __restrict__ maskb,
    const float* __restrict__ s, const float* __restrict__ t,
    float* __restrict__ m) {
  __shared__ float red[4];
  const int h = blockIdx.y;
  const int row = blockIdx.x;
  const int tid = threadIdx.x;
  const int wv = tid >> 6, lane = tid & 63;
  const float* tb = t + h * 4096;
  const u64* mrow = maskb + (size_t)row * 64;
  float tmax = -INFINITY;
#pragma unroll
  for (int i = 0; i < 4; ++i) {
    int jb = i * 1024 + tid * 4;
    u64 w = mrow[jb >> 6];
    int sh = jb & 63;
    float4 tv = *(const float4*)(tb + jb);
    if ((w >> sh) & 1ull) tmax = fmaxf(tmax, tv.x);
    if ((w >> (sh + 1)) & 1ull) tmax = fmaxf(tmax, tv.y);
    if ((w >> (sh + 2)) & 1ull) tmax = fmaxf(tmax, tv.z);
    if ((w >> (sh + 3)) & 1ull) tmax = fmaxf(tmax, tv.w);
  }
#pragma unroll
  for (int o = 32; o; o >>= 1) tmax = fmaxf(tmax, __shfl_xor(tmax, o));
  if (lane == 0) red[wv] = tmax;
  __syncthreads();
  if (tid == 0) {
    tmax = fmaxf(fmaxf(red[0], red[1]), fmaxf(red[2], red[3]));
    float si = s[h * 4096 + row];
    float e0 = si + tmax;
    float mi = fmaxf(e0, 0.2f * e0);
    if (tmax == -INFINITY) mi = 0.0f;
    m[h * 4096 + row] = mi;
  }
}

// ---- one P tile slice (8 elements) for row il, cols jb*64+jc..+7; returns psum part
__device__ __forceinline__ float p_tile(const float* __restrict__ tb,
    const u64* __restrict__ mrow, int jb, int jc, float c1, float c2,
    u16* __restrict__ dst) {
  const u64 w = mrow[jb];
  const u32 w32 = (u32)(w >> jc);
  float tv[8];
  const float4* tp = (const float4*)(tb + jb * 64 + jc);
  *(float4*)&tv[0] = tp[0];
  *(float4*)&tv[4] = tp[1];
  u32 pk[4];
  float ps = 0.0f;
#pragma unroll
  for (int q = 0; q < 4; ++q) {
    float t0 = tv[2 * q], t1 = tv[2 * q + 1];
    float p0 = exp2f(fmaxf(t0 + c1, fmaf(0.2f, t0, c2)));
    p0 = (w32 & (1u << (2 * q))) ? p0 : 0.0f;
    float p1 = exp2f(fmaxf(t1 + c1, fmaf(0.2f, t1, c2)));
    p1 = (w32 & (1u << (2 * q + 1))) ? p1 : 0.0f;
    ps += p0 + p1;
    union { __hip_bfloat162 h; u32 u; } cv;
    cv.h = __float22bfloat162_rn(make_float2(p0, p1));
    pk[q] = cv.u;
  }
  *(uint4*)dst = *(uint4*)&pk[0];
  return ps;
}

// ---------------- masked-softmax aggregation, 32-row tiles, 2 jb per barrier
// hpT in FRAGMENT layout; 16 coalesced 1 KB B-fragment loads per interval.
// Interval: issue rb(jb,jb+1) -> P(jb+2),P(jb+3) VALU hides latency ->
// MFMA(jb),MFMA(jb+1) -> ONE barrier. No value crosses a barrier.
__global__ __launch_bounds__(256) void k_agg(const u16* __restrict__ hpT,
    const u64* __restrict__ maskb, const float* __restrict__ s, const float* __restrict__ t,
    const float* __restrict__ m, float* __restrict__ sumF,
    u16* __restrict__ outB, float* __restrict__ outF,
    int out_ld, int stats_stride, int do_relu, int use_atomic) {
  __shared__ u16 Pt[2][2][32 * 72];
  __shared__ float linv_sh[32];

  const int tid = threadIdx.x;
  const int wv = tid >> 6;
  const int lane = tid & 63;
  const int i0 = blockIdx.x * 32;
  const int gy = blockIdx.y;

  const u16* hbF = hpT + ((size_t)gy << 20);
  const float* sb = s + gy * stats_stride;
  const float* tb = t + gy * stats_stride;
  const float* mb = m + gy * stats_stride;

  const int il = tid >> 3;           // local row 0..31
  const int jc = (tid & 7) * 8;      // 8-wide j chunk
  const float si = sb[i0 + il];
  const float mi = mb[i0 + il];
  const float c1 = si - mi;
  const float c2 = 0.2f * si - mi;
  const u64* mrow = maskb + (size_t)(i0 + il) * 64;

  const int lr = lane & 15;
  const int lq = lane >> 4;

  v4f acc[2][4] = {};
  float psum = 0.0f;

  const int njb = 64 / gridDim.z;
  const int jb0 = blockIdx.z * njb;
  const int jbend = jb0 + njb;

  // per-wave fragment base: [jb][kk2][wv][ft][lane] (u16 units)
  const u16* fb = hbF + wv * 2048 + lane * 8;

  // ---- prologue: P(jb0), P(jb0+1)
  psum += p_tile(tb, mrow, jb0, jc, c1, c2, &Pt[0][0][il * 72 + jc]);
  psum += p_tile(tb, mrow, jb0 + 1, jc, c1, c2, &Pt[0][1][il * 72 + jc]);
  __syncthreads();

  int cur = 0;
  for (int jb = jb0; jb < jbend; jb += 2) {
    // 1. issue 16 B-fragment loads for jb, jb+1
    v8s rb[2][2][4];
#pragma unroll
    for (int sub = 0; sub < 2; ++sub) {
      const u16* fj = fb + (size_t)(jb + sub) * 16384;
#pragma unroll
      for (int kk2 = 0; kk2 < 2; ++kk2)
#pragma unroll
        for (int ft = 0; ft < 4; ++ft)
          rb[sub][kk2][ft] = *(const v8s*)(fj + kk2 * 8192 + ft * 512);
    }

    // 2. P(jb+2), P(jb+3) -> Pt[cur^1]  (VALU covers the 16 loads above)
    if (jb + 2 < jbend) {
      psum += p_tile(tb, mrow, jb + 2, jc, c1, c2, &Pt[cur ^ 1][0][il * 72 + jc]);
      psum += p_tile(tb, mrow, jb + 3, jc, c1, c2, &Pt[cur ^ 1][1][il * 72 + jc]);
    }

    // 3. MFMA for both sub-tiles
#pragma unroll
    for (int sub = 0; sub < 2; ++sub) {
#pragma unroll
      for (int kk2 = 0; kk2 < 2; ++kk2) {
        v8s af[2];
#pragma unroll
        for (int it = 0; it < 2; ++it)
          af[it] = *(const v8s*)&Pt[cur][sub][(it * 16 + lr) * 72 + kk2 * 32 + lq * 8];
#pragma unroll
        for (int it = 0; it < 2; ++it)
#pragma unroll
          for (int ft = 0; ft < 4; ++ft)
            acc[it][ft] = __builtin_amdgcn_mfma_f32_16x16x32_bf16(af[it], rb[sub][kk2][ft], acc[it][ft], 0, 0, 0);
      }
    }
    __syncthreads();
    cur ^= 1;
  }

  // row-sum reduce over the 8 threads of each P-row (consecutive lanes)
  psum += __shfl_xor(psum, 1);
  psum += __shfl_xor(psum, 2);
  psum += __shfl_xor(psum, 4);
  if ((tid & 7) == 0) {
    if (use_atomic) {
      if (gy == 0) atomicAdd(&sumF[i0 + il], psum);
    } else {
      linv_sh[il] = psum > 0.0f ? 1.0f / psum : 0.0f;
    }
  }
  __syncthreads();

#pragma unroll
  for (int it = 0; it < 2; ++it)
#pragma unroll
    for (int ft = 0; ft < 4; ++ft)
#pragma unroll
      for (int r = 0; r < 4; ++r) {
        int ilocal = it * 16 + lq * 4 + r;
        int col = gy * 256 + wv * 64 + ft * 16 + lr;
        if (use_atomic) {
          atomicAdd(&outF[(size_t)(i0 + ilocal) * out_ld + col], acc[it][ft][r]);
        } else {
          float v = acc[it][ft][r] * linv_sh[ilocal];
          if (do_relu) v = fmaxf(v, 0.0f);
          outB[(size_t)(i0 + ilocal) * out_ld + col] = f2bf(v);
        }
      }
}

// ---------------- finalize j-split partials (divide by accumulated row sums)
__global__ __launch_bounds__(256) void k_fin_bf(const float* __restrict__ outF,
    const float* __restrict__ sums, u16* __restrict__ outB, int F, int do_relu) {
  size_t idx = (size_t)blockIdx.x * 256 + threadIdx.x;
  int row = (int)(idx / F);
  float sm = sums[row];
  float linv = sm > 0.0f ? 1.0f / sm : 0.0f;
  float v = outF[idx] * linv;
  if (do_relu) v = fmaxf(v, 0.0f);
  outB[idx] = f2bf(v);
}
__global__ __launch_bounds__(256) void k_fin_f32(float* __restrict__ outF,
    const float* __restrict__ sums, int F) {
  size_t idx = (size_t)blockIdx.x * 256 + threadIdx.x;
  int row = (int)(idx / F);
  float sm = sums[row];
  float linv = sm > 0.0f ? 1.0f / sm : 0.0f;
  outF[idx] *= linv;
}

// ---------------- GroupNorm(1 group over everything) reduce + apply (in place)
// Atomic-contention fix (round 12): 256 WGs, wave-reduce -> LDS cross-wave
// reduce -> ONE thread per WG atomicAdds = 512 atomics total.
__global__ __launch_bounds__(256) void k_gn_reduce(const u16* __restrict__ h4,
                                                   float* __restrict__ accv) {
  __shared__ float redS[8];
  const size_t total = (size_t)4096 * 1536 / 8;
  const int tid = threadIdx.x;
  const int wv = tid >> 6;
  float sm = 0.0f, s2 = 0.0f;
  for (size_t c = (size_t)blockIdx.x * 256 + tid; c < total; c += (size_t)gridDim.x * 256) {
    uint4 u = ((const uint4*)h4)[c];
    u16 us[8];
    *(uint4*)us = u;
#pragma unroll
    for (int k = 0; k < 8; ++k) {
      float v = bf2f(us[k]);
      sm += v;
      s2 += v * v;
    }
  }
#pragma unroll
  for (int o = 32; o; o >>= 1) { sm += __shfl_xor(sm, o); s2 += __shfl_xor(s2, o); }
  if ((tid & 63) == 0) { redS[wv * 2] = sm; redS[wv * 2 + 1] = s2; }
  __syncthreads();
  if (tid == 0) {
    float tsm = redS[0] + redS[2] + redS[4] + redS[6];
    float ts2 = redS[1] + redS[3] + redS[5] + redS[7];
    atomicAdd(&accv[0], tsm);
    atomicAdd(&accv[1], ts2);
  }
}

__global__ __launch_bounds__(256) void k_gn_apply(const u16* __restrict__ h4,
    const float* __restrict__ accv, const float* __restrict__ gw,
    const float* __restrict__ gb, u16* __restrict__ h5) {
  const float Mc = 4096.0f * 1536.0f;
  float mu = accv[0] * (1.0f / Mc);
  float var = (accv[1] - Mc * mu * mu) * (1.0f / (Mc - 1.0f));
  float rstd = rsqrtf(var + 1e-5f);
  size_t c = (size_t)blockIdx.x * 256 + threadIdx.x;
  uint4 u = ((const uint4*)h4)[c];
  u16 us[8], os[8];
  *(uint4*)us = u;
  int col0 = (int)((c * 8) % 1536);
#pragma unroll
  for (int k = 0; k < 8; ++k) {
    float v = (bf2f(us[k]) - mu) * rstd * gw[col0 + k] + gb[col0 + k];
    os[k] = f2bf(v);
  }
  ((uint4*)h5)[c] = *(uint4*)os;
}

extern "C" void kernel_launch(void* const* d_in, const int* in_sizes, int n_in,
                              void* d_out, int out_size, void* d_ws, size_t ws_size,
                              hipStream_t stream) {
  const float* x = (const float*)d_in[0];
  const int* adj = (const int*)d_in[1];
  const float* lin1_w = (const float*)d_in[2];
  const float* lin1_b = (const float*)d_in[3];
  const float* lin2_w = (const float*)d_in[4];
  const float* lin2_b = (const float*)d_in[5];
  const float* conv1_W = (const float*)d_in[6];
  const float* conv1_a = (const float*)d_in[7];
  const float* att_W = (const float*)d_in[8];
  const float* att_a = (const float*)d_in[9];
  const float* gn_w = (const float*)d_in[10];
  const float* gn_b = (const float*)d_in[11];
  const float* conv2_W = (const float*)d_in[12];
  const float* conv2_a = (const float*)d_in[13];
  float* out = (float*)d_out;   // reference output dtype: float32

  // ---- arena, adaptive: big path needs 32.5 MB (6-head batch), small path 23.75 MB
  const bool big = ws_size >= (34ull << 20);
  const int B = big ? 6 : 2;           // heads per batch
  char* base = (char*)d_ws;
  const size_t MB = 1ull << 20;
  u64* maskb = (u64*)base;                                   // 2 MB
  u16* hpT = (u16*)(base + 2 * MB);                          // big 12 / small 4 MB
  u16* hC  = (u16*)(base + (big ? 14 : 6) * MB);             // 12 MB (h4/h5)
  u16* h3  = (u16*)(base + (big ? 26 : 18) * MB);            // 4 MB
  u16* h2  = (u16*)(base + (big ? 30 : 22) * MB);            // 0.5 MB
  u16* wt  = (u16*)(base + (big ? 30 : 22) * MB + 512 * 1024);      // 1.5 MB
  float* sA = (float*)(base + (big ? 32 : 24) * MB);         // stats 0.5 MB
  float* tA = sA + 6 * 4096;
  float* mA = tA + 6 * 4096;
  float* lA = mA + 6 * 4096;      // row-sum accumulator for j-split launches
  float* wab = lA + 6 * 4096;
  float* gacc = wab + 8192;
  float* outF1 = (float*)hC;   // conv1 fp32 partials (8 MB) — h4 not yet live

  hipMemsetAsync(gacc, 0, 16, stream);
  hipMemsetAsync(out, 0, (size_t)4096 * 256 * 4, stream);
  hipMemsetAsync(outF1, 0, (size_t)4096 * 512 * 4, stream);
  hipMemsetAsync(lA, 0, 4096 * 4, stream);

  k_pack_mask<<<dim3(65536), dim3(256), 0, stream>>>(adj, maskb);
  k_lin12<<<dim3(4096), dim3(64), 0, stream>>>(x, lin1_w, lin1_b, lin2_w, lin2_b, h2);

  // ---- conv1 (F=512): j-split Z=2, 512 WGs
  k_transpose<<<dim3(128), dim3(256), 0, stream>>>(conv1_W, wt, 64, 512, 64 * 512);
  k_gemm_bt<<<dim3(32, 4), dim3(256), 0, stream>>>(wt, h2, hpT, 512, 4096, 64);
  k_wa<<<dim3(1), dim3(128), 0, stream>>>(conv1_W, conv1_a, wab, 64, 512, 128);
  k_st2<<<dim3(1024, 1), dim3(256), 0, stream>>>(h2, wab, 64, sA, tA);
  k_rowstats<<<dim3(4096, 1), dim3(256), 0, stream>>>(maskb, sA, tA, mA);
  k_agg<<<dim3(128, 2, 2), dim3(256), 0, stream>>>(hpT, maskb, sA, tA, mA, lA,
                                                   (u16*)0, outF1, 512, 0, 0, 1);
  k_fin_bf<<<dim3(8192), dim3(256), 0, stream>>>(outF1, lA, h3, 512, 1);

  // ---- 6 heads (F=256), batched B at a time; stats batched once
  k_wa<<<dim3(24), dim3(256), 0, stream>>>(att_W, att_a, wab, 512, 256, 6144);
  k_st2<<<dim3(1024, 6), dim3(256), 0, stream>>>(h3, wab, 512, sA, tA);
  k_rowstats<<<dim3(4096, 6), dim3(256), 0, stream>>>(maskb, sA, tA, mA);
  for (int bh = 0; bh < 6; bh += B) {
    k_transpose<<<dim3(B * 512), dim3(256), 0, stream>>>(att_W + (size_t)bh * 512 * 256,
                                                         wt, 512, 256, B * 512 * 256);
    k_gemm_bt<<<dim3(32, 2 * B), dim3(256), 0, stream>>>(wt, h3, hpT, B * 256, 4096, 512);
    k_agg<<<dim3(128, B, 1), dim3(256), 0, stream>>>(hpT, maskb,
        sA + bh * 4096, tA + bh * 4096, mA + bh * 4096, (float*)0,
        hC + bh * 256, (float*)0, 1536, 4096, 1, 0);
  }

  // ---- GroupNorm (in place on hC)
  k_gn_reduce<<<dim3(256), dim3(256), 0, stream>>>(hC, gacc);
  k_gn_apply<<<dim3(3072), dim3(256), 0, stream>>>(hC, gacc, gn_w, gn_b, hC);

  // ---- conv2 (F=256): j-split Z=4, atomics straight into f32 d_out
  k_transpose<<<dim3(1536), dim3(256), 0, stream>>>(conv2_W, wt, 1536, 256, 1536 * 256);
  k_gemm_bt<<<dim3(32, 2), dim3(256), 0, stream>>>(wt, hC, hpT, 256, 4096, 1536);
  k_wa<<<dim3(12), dim3(256), 0, stream>>>(conv2_W, conv2_a, wab, 1536, 256, 3072);
  k_st2<<<dim3(1024, 1), dim3(256), 0, stream>>>(hC, wab, 1536, sA, tA);
  k_rowstats<<<dim3(4096, 1), dim3(256), 0, stream>>>(maskb, sA, tA, mA);
  hipMemsetAsync(lA, 0, 4096 * 4, stream);
  k_agg<<<dim3(128, 1, 4), dim3(256), 0, stream>>>(hpT, maskb, sA, tA, mA, lA,
                                                   (u16*)0, out, 256, 0, 0, 1);
  k_fin_f32<<<dim3(4096), dim3(256), 0, stream>>>(out, lA, 256);
}